// Round 1
// baseline (467.209 us; speedup 1.0000x reference)
//
#include <hip/hip_runtime.h>
#include <math.h>

#define HW 16384
#define NPTS 1024
#define BLK 128
#define KSTEP 32

// log(512) in double
#define LOG_N 6.2383246250395075
#define RHO_C 0.09

// ---------------------------------------------------------------------------
// G = P * P^T partials, P = [normed_density; gt] (1024 x 16384 fp32).
// Tile 128x128, split-K over gridDim.z chunks, fp32 accumulate per chunk.
// ---------------------------------------------------------------------------
__global__ __launch_bounds__(256)
void gemm_partial_k(const float* __restrict__ nd, const float* __restrict__ gt,
                    float* __restrict__ part) {
  __shared__ float As[KSTEP][BLK + 4];
  __shared__ float Bs[KSTEP][BLK + 4];
  const int ti = blockIdx.x, tj = blockIdx.y, c = blockIdx.z;
  const int kchunk = HW / gridDim.z;
  const int t = threadIdx.x;
  const int tx = t & 15, ty = t >> 4;
  const float* __restrict__ Abase = (ti < 4) ? (nd + (size_t)ti * BLK * HW)
                                             : (gt + (size_t)(ti - 4) * BLK * HW);
  const float* __restrict__ Bbase = (tj < 4) ? (nd + (size_t)tj * BLK * HW)
                                             : (gt + (size_t)(tj - 4) * BLK * HW);
  float acc[8][8];
#pragma unroll
  for (int i = 0; i < 8; ++i)
#pragma unroll
    for (int j = 0; j < 8; ++j) acc[i][j] = 0.f;

  const int lr = t >> 3;        // 0..31
  const int lc = (t & 7) << 2;  // 0,4,...,28
  const int k0 = c * kchunk;
  for (int ks = 0; ks < kchunk; ks += KSTEP) {
#pragma unroll
    for (int rr = 0; rr < 4; ++rr) {
      const int row = lr + rr * 32;
      const float4 va = *(const float4*)(Abase + (size_t)row * HW + k0 + ks + lc);
      As[lc + 0][row] = va.x; As[lc + 1][row] = va.y;
      As[lc + 2][row] = va.z; As[lc + 3][row] = va.w;
      const float4 vb = *(const float4*)(Bbase + (size_t)row * HW + k0 + ks + lc);
      Bs[lc + 0][row] = vb.x; Bs[lc + 1][row] = vb.y;
      Bs[lc + 2][row] = vb.z; Bs[lc + 3][row] = vb.w;
    }
    __syncthreads();
#pragma unroll
    for (int kk = 0; kk < KSTEP; ++kk) {
      const float4 a0 = *(const float4*)(&As[kk][ty * 8]);
      const float4 a1 = *(const float4*)(&As[kk][ty * 8 + 4]);
      const float4 b0 = *(const float4*)(&Bs[kk][tx * 8]);
      const float4 b1 = *(const float4*)(&Bs[kk][tx * 8 + 4]);
      const float a[8] = {a0.x, a0.y, a0.z, a0.w, a1.x, a1.y, a1.z, a1.w};
      const float b[8] = {b0.x, b0.y, b0.z, b0.w, b1.x, b1.y, b1.z, b1.w};
#pragma unroll
      for (int i = 0; i < 8; ++i)
#pragma unroll
        for (int j = 0; j < 8; ++j) acc[i][j] = fmaf(a[i], b[j], acc[i][j]);
    }
    __syncthreads();
  }
  float* __restrict__ dst = part + (size_t)c * NPTS * NPTS;
#pragma unroll
  for (int i = 0; i < 8; ++i) {
    const int grow = ti * BLK + ty * 8 + i;
    float4 o0 = make_float4(acc[i][0], acc[i][1], acc[i][2], acc[i][3]);
    float4 o1 = make_float4(acc[i][4], acc[i][5], acc[i][6], acc[i][7]);
    float4* p = (float4*)(dst + (size_t)grow * NPTS + tj * BLK + tx * 8);
    p[0] = o0;
    p[1] = o1;
  }
}

// ---------------------------------------------------------------------------
// Reduce split-K partials in fp64, emit fp32 G and its diagonal.
// ---------------------------------------------------------------------------
__global__ __launch_bounds__(256)
void reduce_partials_k(const float* __restrict__ part, float* __restrict__ G,
                       float* __restrict__ diag, int nsplit) {
  const size_t e = (size_t)blockIdx.x * 256 + threadIdx.x;
  double s = 0.0;
  for (int c = 0; c < nsplit; ++c) s += (double)part[(size_t)c * NPTS * NPTS + e];
  const float g = (float)s;
  G[e] = g;
  const int row = (int)(e >> 10), col = (int)(e & 1023);
  if (row == col) diag[row] = g;
}

// ---------------------------------------------------------------------------
// One symmetric Sinkhorn phase: 4 potentials x 512 rows = 2048 wave-tasks.
// pot layout: [0]=f_ba, [1]=g_ab, [2]=f_aa, [3]=g_bb (512 doubles each).
// arg_j = -log(512) + (pot_old[j] - C(row, col_base+j)) / eps
// out   = damp * (-eps * LSE_j(arg)) ; averaged with old value in loop phases.
// ---------------------------------------------------------------------------
__global__ __launch_bounds__(64)
void sinkhorn_phase_k(const float* __restrict__ G, const float* __restrict__ diag,
                      const double* __restrict__ src, double* __restrict__ dst,
                      double eps, double inv_eps, double damp, int use_pot,
                      int do_avg) {
  const int id = blockIdx.x;
  const int which = id >> 9;
  const int r = id & 511;
  int row_pt, col_base, pot_idx;
  if (which == 0)      { row_pt = r;       col_base = 512; pot_idx = 1; } // f_ba <- g_ab
  else if (which == 1) { row_pt = 512 + r; col_base = 0;   pot_idx = 0; } // g_ab <- f_ba
  else if (which == 2) { row_pt = r;       col_base = 0;   pot_idx = 2; } // f_aa <- f_aa
  else                 { row_pt = 512 + r; col_base = 512; pot_idx = 3; } // g_bb <- g_bb

  const int lane = threadIdx.x;
  const double dr = (double)diag[row_pt];
  const double* __restrict__ pot = src + pot_idx * 512;
  const float* __restrict__ Grow = G + (size_t)row_pt * NPTS + col_base;
  const float* __restrict__ dcol = diag + col_base;

  double arg[8];
  double m = -1.0e300;
#pragma unroll
  for (int u = 0; u < 8; ++u) {
    const int j = lane + u * 64;
    const double C = 0.5 * (dr + (double)dcol[j]) - (double)Grow[j];
    const double p = use_pot ? pot[j] : 0.0;
    const double a = (p - C) * inv_eps - LOG_N;
    arg[u] = a;
    m = fmax(m, a);
  }
#pragma unroll
  for (int off = 32; off > 0; off >>= 1) m = fmax(m, __shfl_xor(m, off));
  double s = 0.0;
#pragma unroll
  for (int u = 0; u < 8; ++u) s += exp(arg[u] - m);
#pragma unroll
  for (int off = 32; off > 0; off >>= 1) s += __shfl_xor(s, off);
  if (lane == 0) {
    const double lse = m + log(s);
    const double val = -eps * lse * damp;
    dst[which * 512 + r] = do_avg ? 0.5 * (src[which * 512 + r] + val) : val;
  }
}

// ---------------------------------------------------------------------------
// Debiased unbalanced Sinkhorn loss.
// ---------------------------------------------------------------------------
__global__ __launch_bounds__(256)
void loss_k(const double* __restrict__ pot, float* __restrict__ out, int out_size,
            double w) {
  const int t = threadIdx.x;
  double s = 0.0;
  for (int i = t; i < 512; i += 256) {
    const double f_ba = pot[i];
    const double g_ab = pot[512 + i];
    const double f_aa = pot[1024 + i];
    const double g_bb = pot[1536 + i];
    s += (exp(-f_aa / RHO_C) - exp(-f_ba / RHO_C)) +
         (exp(-g_bb / RHO_C) - exp(-g_ab / RHO_C));
  }
#pragma unroll
  for (int off = 32; off > 0; off >>= 1) s += __shfl_xor(s, off);
  __shared__ double wsum[4];
  const int wv = t >> 6;
  if ((t & 63) == 0) wsum[wv] = s;
  __syncthreads();
  if (t == 0) {
    const double tot = wsum[0] + wsum[1] + wsum[2] + wsum[3];
    out[0] = (float)(w * tot * (1.0 / 512.0));
    for (int i = 1; i < out_size; ++i) out[i] = 0.f;
  }
}

extern "C" void kernel_launch(void* const* d_in, const int* in_sizes, int n_in,
                              void* d_out, int out_size, void* d_ws, size_t ws_size,
                              hipStream_t stream) {
  const float* nd = (const float*)d_in[1];  // normed_density [512*16384]
  const float* gt = (const float*)d_in[2];  // gt             [512*16384]
  float* out = (float*)d_out;
  char* ws = (char*)d_ws;

  const size_t GM = (size_t)NPTS * NPTS;  // 1048576 elements
  int nsplit = 8;
  while (nsplit > 1 && (size_t)(nsplit + 1) * GM * 4 + 65536 > ws_size) nsplit >>= 1;

  float* part = (float*)ws;                                     // nsplit * 4 MB
  float* G = (float*)(ws + (size_t)nsplit * GM * 4);            // 4 MB
  float* diag = (float*)(ws + (size_t)(nsplit + 1) * GM * 4);   // 4 KB
  double* pots = (double*)(ws + (size_t)(nsplit + 1) * GM * 4 + 8192);  // 32 KB

  gemm_partial_k<<<dim3(8, 8, nsplit), 256, 0, stream>>>(nd, gt, part);
  reduce_partials_k<<<(int)(GM / 256), 256, 0, stream>>>(part, G, diag, nsplit);

  // geomloss epsilon schedule: [diameter^2] + exp(arange(2ln1, 2ln0.01, 2ln0.5)) + [blur^2]
  const double eps_list[9] = {1.0, 1.0, 0.25, 0.0625, 0.015625,
                              0.00390625, 0.0009765625, 0.000244140625, 1e-4};

  double* p0 = pots;
  double* p1 = pots + 4 * 512;

  {  // init at eps0 = 1.0, no inner potentials, no averaging
    const double eps = 1.0;
    const double d = 1.0 / (1.0 + eps / RHO_C);
    sinkhorn_phase_k<<<2048, 64, 0, stream>>>(G, diag, p1, p0, eps, 1.0 / eps, d, 0, 0);
  }
  double* src = p0;
  double* dst = p1;
  for (int k = 0; k < 9; ++k) {  // symmetric averaged updates
    const double eps = eps_list[k];
    const double d = 1.0 / (1.0 + eps / RHO_C);
    sinkhorn_phase_k<<<2048, 64, 0, stream>>>(G, diag, src, dst, eps, 1.0 / eps, d, 1, 1);
    double* tmp = src; src = dst; dst = tmp;
  }
  {  // final extrapolation at blur^2, no averaging
    const double eps = 1e-4;
    const double d = 1.0 / (1.0 + eps / RHO_C);
    sinkhorn_phase_k<<<2048, 64, 0, stream>>>(G, diag, src, dst, eps, 1.0 / eps, d, 1, 0);
    double* tmp = src; src = dst; dst = tmp;
  }
  loss_k<<<1, 256, 0, stream>>>(src, out, out_size, RHO_C + 1e-4 * 0.5);
}

// Round 2
// 194.553 us; speedup vs baseline: 2.4014x; 2.4014x over previous
//
#include <hip/hip_runtime.h>
#include <math.h>

#define HW 16384
#define NPTS 1024
#define LOG_N 6.2383246250395075
#define RHO_C 0.09
#define SCALE_F 16384.0f
#define INV_SCALE2 3.725290298461914e-09  // 2^-28, exact

typedef _Float16 f16x8 __attribute__((ext_vector_type(8)));
typedef float f32x4 __attribute__((ext_vector_type(4)));

typedef __attribute__((address_space(1))) const void gvoid_t;
typedef __attribute__((address_space(3))) void svoid_t;

// ---------------------------------------------------------------------------
// Convert fp32 P=[nd;gt] (1024 x 16384) into scaled fp16 hi/lo split, stored
// K-tiled: hi_t[k64][row][64] with each row's eight 8-elem groups placed at
// position g ^ (row&7) (pre-swizzled so the GEMM's linear global_load_lds
// produces a bank-conflict-free LDS image).  x_s = x*2^14 = hi + lo (+2^-22).
// ---------------------------------------------------------------------------
__global__ __launch_bounds__(256)
void convert_split_k(const float* __restrict__ nd, const float* __restrict__ gt,
                     _Float16* __restrict__ hi_t, _Float16* __restrict__ lo_t) {
  const int tid = blockIdx.x * 256 + threadIdx.x;  // 0 .. 262143
  const int r = tid & 1023;
  const int k64 = tid >> 10;                       // 0..255
  const float* __restrict__ src =
      (r < 512 ? nd + (size_t)r * HW : gt + (size_t)(r - 512) * HW) + k64 * 64;
  const size_t obase = ((size_t)k64 * 1024 + r) * 64;
  const int sw = r & 7;
#pragma unroll
  for (int g = 0; g < 8; ++g) {
    const float4 v0 = *(const float4*)(src + g * 8);
    const float4 v1 = *(const float4*)(src + g * 8 + 4);
    const float x[8] = {v0.x, v0.y, v0.z, v0.w, v1.x, v1.y, v1.z, v1.w};
    f16x8 h, l;
#pragma unroll
    for (int j = 0; j < 8; ++j) {
      const float xs = x[j] * SCALE_F;
      const _Float16 hh = (_Float16)xs;
      h[j] = hh;
      l[j] = (_Float16)(xs - (float)hh);
    }
    *(f16x8*)(hi_t + obase + (size_t)(g ^ sw) * 8) = h;
    *(f16x8*)(lo_t + obase + (size_t)(g ^ sw) * 8) = l;
  }
}

// ---------------------------------------------------------------------------
// G_s = P_s * P_s^T via 16x16x32 f16 MFMA, 3 passes (hihi + hilo + lohi).
// 128x128 tile, BK=64, 4 waves (2x2), split-K over gridDim.z.
// LDS loaded with global_load_lds width=16 (linear dest, pre-swizzled src).
// ---------------------------------------------------------------------------
__global__ __launch_bounds__(256)
void gemm_mfma_k(const _Float16* __restrict__ hi_t, const _Float16* __restrict__ lo_t,
                 float* __restrict__ part) {
  __shared__ __align__(16) _Float16 Ahi[128 * 64];
  __shared__ __align__(16) _Float16 Alo[128 * 64];
  __shared__ __align__(16) _Float16 Bhi[128 * 64];
  __shared__ __align__(16) _Float16 Blo[128 * 64];

  const int ti = blockIdx.x, tj = blockIdx.y, c = blockIdx.z;
  const int nkt = 256 / gridDim.z;  // k64-tiles per split-K chunk
  const int t = threadIdx.x;
  const int lane = t & 63, w = t >> 6;
  const int wr = w >> 1, wc = w & 1;

  f32x4 acc[4][4];
#pragma unroll
  for (int m = 0; m < 4; ++m)
#pragma unroll
    for (int n = 0; n < 4; ++n) acc[m][n] = (f32x4){0.f, 0.f, 0.f, 0.f};

  const int rlow = lane & 15, g0 = lane >> 4;
  const int kt0 = c * nkt;

  for (int ks = 0; ks < nkt; ++ks) {
    const size_t ktbase = (size_t)(kt0 + ks) * (1024 * 64);
    const _Float16* __restrict__ sAh = hi_t + ktbase + (size_t)ti * 128 * 64;
    const _Float16* __restrict__ sAl = lo_t + ktbase + (size_t)ti * 128 * 64;
    const _Float16* __restrict__ sBh = hi_t + ktbase + (size_t)tj * 128 * 64;
    const _Float16* __restrict__ sBl = lo_t + ktbase + (size_t)tj * 128 * 64;
    // 16 KB per buffer = 16 x 1KB chunks; wave w takes chunks 4w..4w+3
#pragma unroll
    for (int q = 0; q < 4; ++q) {
      const int off = (w * 4 + q) * 1024 + lane * 16;  // bytes
      __builtin_amdgcn_global_load_lds((gvoid_t*)((const char*)sAh + off),
                                       (svoid_t*)((char*)Ahi + (w * 4 + q) * 1024), 16, 0, 0);
      __builtin_amdgcn_global_load_lds((gvoid_t*)((const char*)sAl + off),
                                       (svoid_t*)((char*)Alo + (w * 4 + q) * 1024), 16, 0, 0);
      __builtin_amdgcn_global_load_lds((gvoid_t*)((const char*)sBh + off),
                                       (svoid_t*)((char*)Bhi + (w * 4 + q) * 1024), 16, 0, 0);
      __builtin_amdgcn_global_load_lds((gvoid_t*)((const char*)sBl + off),
                                       (svoid_t*)((char*)Blo + (w * 4 + q) * 1024), 16, 0, 0);
    }
    __syncthreads();

#pragma unroll
    for (int kk = 0; kk < 2; ++kk) {
      const int g = kk * 4 + g0;  // 8-elem group index within the 64-k row
      f16x8 fah[4], fal[4], fbh[4], fbl[4];
#pragma unroll
      for (int m = 0; m < 4; ++m) {
        const int ra = wr * 64 + m * 16 + rlow;
        const int pa = (g ^ (ra & 7)) * 8;
        fah[m] = *(const f16x8*)(Ahi + ra * 64 + pa);
        fal[m] = *(const f16x8*)(Alo + ra * 64 + pa);
        const int rb = wc * 64 + m * 16 + rlow;
        const int pb = (g ^ (rb & 7)) * 8;
        fbh[m] = *(const f16x8*)(Bhi + rb * 64 + pb);
        fbl[m] = *(const f16x8*)(Blo + rb * 64 + pb);
      }
#pragma unroll
      for (int m = 0; m < 4; ++m)
#pragma unroll
        for (int n = 0; n < 4; ++n) {
          acc[m][n] = __builtin_amdgcn_mfma_f32_16x16x32_f16(fah[m], fbh[n], acc[m][n], 0, 0, 0);
          acc[m][n] = __builtin_amdgcn_mfma_f32_16x16x32_f16(fal[m], fbh[n], acc[m][n], 0, 0, 0);
          acc[m][n] = __builtin_amdgcn_mfma_f32_16x16x32_f16(fah[m], fbl[n], acc[m][n], 0, 0, 0);
        }
    }
    __syncthreads();
  }

  // epilogue: C/D layout col = lane&15, row = (lane>>4)*4 + q (m89-verified)
  float* __restrict__ dst = part + (size_t)c * NPTS * NPTS;
  const int colb = tj * 128 + wc * 64 + rlow;
  const int rowb = ti * 128 + wr * 64 + g0 * 4;
#pragma unroll
  for (int m = 0; m < 4; ++m)
#pragma unroll
    for (int q = 0; q < 4; ++q) {
      const int row = rowb + m * 16 + q;
#pragma unroll
      for (int n = 0; n < 4; ++n)
        dst[(size_t)row * NPTS + colb + n * 16] = acc[m][n][q];
    }
}

// ---------------------------------------------------------------------------
// Reduce split-K partials in fp64, unscale by 2^-28, emit fp32 G (in-place
// over part[0]) and its diagonal.
// ---------------------------------------------------------------------------
__global__ __launch_bounds__(256)
void reduce_partials_k(float* __restrict__ part, float* __restrict__ diag, int nsplit) {
  const size_t e = (size_t)blockIdx.x * 256 + threadIdx.x;
  double s = 0.0;
  for (int c = 0; c < nsplit; ++c) s += (double)part[(size_t)c * NPTS * NPTS + e];
  const float g = (float)(s * INV_SCALE2);
  part[e] = g;
  const int row = (int)(e >> 10), col = (int)(e & 1023);
  if (row == col) diag[row] = g;
}

// ---------------------------------------------------------------------------
// One symmetric Sinkhorn phase: 4 potentials x 512 rows = 2048 wave-tasks.
// ---------------------------------------------------------------------------
__global__ __launch_bounds__(64)
void sinkhorn_phase_k(const float* __restrict__ G, const float* __restrict__ diag,
                      const double* __restrict__ src, double* __restrict__ dst,
                      double eps, double inv_eps, double damp, int use_pot,
                      int do_avg) {
  const int id = blockIdx.x;
  const int which = id >> 9;
  const int r = id & 511;
  int row_pt, col_base, pot_idx;
  if (which == 0)      { row_pt = r;       col_base = 512; pot_idx = 1; } // f_ba <- g_ab
  else if (which == 1) { row_pt = 512 + r; col_base = 0;   pot_idx = 0; } // g_ab <- f_ba
  else if (which == 2) { row_pt = r;       col_base = 0;   pot_idx = 2; } // f_aa <- f_aa
  else                 { row_pt = 512 + r; col_base = 512; pot_idx = 3; } // g_bb <- g_bb

  const int lane = threadIdx.x;
  const double dr = (double)diag[row_pt];
  const double* __restrict__ pot = src + pot_idx * 512;
  const float* __restrict__ Grow = G + (size_t)row_pt * NPTS + col_base;
  const float* __restrict__ dcol = diag + col_base;

  double arg[8];
  double m = -1.0e300;
#pragma unroll
  for (int u = 0; u < 8; ++u) {
    const int j = lane + u * 64;
    const double C = 0.5 * (dr + (double)dcol[j]) - (double)Grow[j];
    const double p = use_pot ? pot[j] : 0.0;
    const double a = (p - C) * inv_eps - LOG_N;
    arg[u] = a;
    m = fmax(m, a);
  }
#pragma unroll
  for (int off = 32; off > 0; off >>= 1) m = fmax(m, __shfl_xor(m, off));
  double s = 0.0;
#pragma unroll
  for (int u = 0; u < 8; ++u) s += exp(arg[u] - m);
#pragma unroll
  for (int off = 32; off > 0; off >>= 1) s += __shfl_xor(s, off);
  if (lane == 0) {
    const double lse = m + log(s);
    const double val = -eps * lse * damp;
    dst[which * 512 + r] = do_avg ? 0.5 * (src[which * 512 + r] + val) : val;
  }
}

// ---------------------------------------------------------------------------
// Debiased unbalanced Sinkhorn loss.
// ---------------------------------------------------------------------------
__global__ __launch_bounds__(256)
void loss_k(const double* __restrict__ pot, float* __restrict__ out, int out_size,
            double w) {
  const int t = threadIdx.x;
  double s = 0.0;
  for (int i = t; i < 512; i += 256) {
    const double f_ba = pot[i];
    const double g_ab = pot[512 + i];
    const double f_aa = pot[1024 + i];
    const double g_bb = pot[1536 + i];
    s += (exp(-f_aa / RHO_C) - exp(-f_ba / RHO_C)) +
         (exp(-g_bb / RHO_C) - exp(-g_ab / RHO_C));
  }
#pragma unroll
  for (int off = 32; off > 0; off >>= 1) s += __shfl_xor(s, off);
  __shared__ double wsum[4];
  const int wv = t >> 6;
  if ((t & 63) == 0) wsum[wv] = s;
  __syncthreads();
  if (t == 0) {
    const double tot = wsum[0] + wsum[1] + wsum[2] + wsum[3];
    out[0] = (float)(w * tot * (1.0 / 512.0));
    for (int i = 1; i < out_size; ++i) out[i] = 0.f;
  }
}

extern "C" void kernel_launch(void* const* d_in, const int* in_sizes, int n_in,
                              void* d_out, int out_size, void* d_ws, size_t ws_size,
                              hipStream_t stream) {
  const float* nd = (const float*)d_in[1];  // normed_density [512*16384]
  const float* gt = (const float*)d_in[2];  // gt             [512*16384]
  float* out = (float*)d_out;
  char* ws = (char*)d_ws;

  const size_t GM = (size_t)NPTS * NPTS;          // 1048576 elements
  const size_t P16 = (size_t)NPTS * HW * 2;       // 32 MB per half
  int nsplit = 8;
  while (nsplit > 1 && 2 * P16 + (size_t)nsplit * GM * 4 + 65536 > ws_size) nsplit >>= 1;

  _Float16* hi_t = (_Float16*)ws;
  _Float16* lo_t = (_Float16*)(ws + P16);
  float* part = (float*)(ws + 2 * P16);           // nsplit * 4 MB; G aliases part[0]
  float* G = part;
  float* diag = (float*)(ws + 2 * P16 + (size_t)nsplit * GM * 4);
  double* pots = (double*)(ws + 2 * P16 + (size_t)nsplit * GM * 4 + 8192);

  convert_split_k<<<1024, 256, 0, stream>>>(nd, gt, hi_t, lo_t);
  gemm_mfma_k<<<dim3(8, 8, nsplit), 256, 0, stream>>>(hi_t, lo_t, part);
  reduce_partials_k<<<(int)(GM / 256), 256, 0, stream>>>(part, diag, nsplit);

  const double eps_list[9] = {1.0, 1.0, 0.25, 0.0625, 0.015625,
                              0.00390625, 0.0009765625, 0.000244140625, 1e-4};

  double* p0 = pots;
  double* p1 = pots + 4 * 512;

  {  // init at eps0 = 1.0, no inner potentials, no averaging
    const double eps = 1.0;
    const double d = 1.0 / (1.0 + eps / RHO_C);
    sinkhorn_phase_k<<<2048, 64, 0, stream>>>(G, diag, p1, p0, eps, 1.0 / eps, d, 0, 0);
  }
  double* src = p0;
  double* dst = p1;
  for (int k = 0; k < 9; ++k) {  // symmetric averaged updates
    const double eps = eps_list[k];
    const double d = 1.0 / (1.0 + eps / RHO_C);
    sinkhorn_phase_k<<<2048, 64, 0, stream>>>(G, diag, src, dst, eps, 1.0 / eps, d, 1, 1);
    double* tmp = src; src = dst; dst = tmp;
  }
  {  // final extrapolation at blur^2, no averaging
    const double eps = 1e-4;
    const double d = 1.0 / (1.0 + eps / RHO_C);
    sinkhorn_phase_k<<<2048, 64, 0, stream>>>(G, diag, src, dst, eps, 1.0 / eps, d, 1, 0);
    double* tmp = src; src = dst; dst = tmp;
  }
  loss_k<<<1, 256, 0, stream>>>(src, out, out_size, RHO_C + 1e-4 * 0.5);
}